// Round 7
// baseline (267.140 us; speedup 1.0000x reference)
//
#include <hip/hip_runtime.h>
#include <hip/hip_bf16.h>

#define Bc 512
#define Lc 512
#define Tc 128
#define GB 16     // batches per block
#define NW 4      // waves per block; wave w owns cols [32w, 32w+32) as 2 interleaved slices
#define PSTR 136  // padded P row stride in bf16 elems (272B): b128 reads slot-uniform, u32 writes 2-way
#define PBUF (GB * PSTR)

typedef __attribute__((ext_vector_type(8))) short bf16x8;
typedef __attribute__((ext_vector_type(4))) float f32x4;
typedef __attribute__((ext_vector_type(2))) float f32x2;

// raw barrier: drain LDS ops only; global prefetches stay in flight
__device__ __forceinline__ void bar_lgkm() {
  asm volatile("s_waitcnt lgkmcnt(0)\n\ts_barrier" ::: "memory");
}

__device__ __forceinline__ unsigned short f2bf_u(float f) {
  __hip_bfloat16 h = __float2bfloat16(f);
  unsigned short us;
  __builtin_memcpy(&us, &h, 2);
  return us;
}
__device__ __forceinline__ short f2bf(float f) { return (short)f2bf_u(f); }

__global__ __launch_bounds__(256, 1) __attribute__((amdgpu_waves_per_eu(1, 2)))
void crf_forward(const float* __restrict__ x,      // [B,L,T]
                 const float* __restrict__ trans,  // [T,T]
                 const float* __restrict__ startT, // [T]
                 const float* __restrict__ endT,   // [T]
                 const int*   __restrict__ labels, // [B,L]
                 const int*   __restrict__ mask,   // [B,L]
                 float* __restrict__ diff_out,     // [B]
                 float* __restrict__ msum_out)     // [B]
{
  __shared__ __align__(16) unsigned short Pl[2 * PBUF]; // double-buffered A-tile
  __shared__ __align__(16) float r_s[2][GB];            // double-buffered rescale bcast
  __shared__ __align__(16) unsigned char mT[Lc][GB];    // transposed mask bytes [t][b]
  __shared__ __align__(16) float c_s[GB];
  __shared__ float score_s[GB];
  __shared__ float msum_s[GB];
  __shared__ float red[GB][NW];

  const int tid  = threadIdx.x;
  const int lane = tid & 63;
  const int w    = tid >> 6;        // wave 0..3
  const int crow = lane & 15;
  const int khi  = lane >> 4;       // 0..3
  const int bg0  = blockIdx.x * GB;
  const int jA   = 32 * w + 2 * crow;  // even col of this lane's pair (jB = jA+1)

  // ---- stage transposed mask bytes ----
  for (int i = tid; i < GB * Lc; i += 256) {
    int bb = i >> 9;
    int t  = i & (Lc - 1);
    mT[t][bb] = (unsigned char)mask[(size_t)(bg0 + bb) * Lc + t];
  }

  // ---- gold-path score + msum: wave w handles local batches 4w..4w+3 ----
  for (int bb = 4 * w; bb < 4 * w + 4; ++bb) {
    const int bglob = bg0 + bb;
    const int* lbp = labels + (size_t)bglob * Lc;
    const int* mkp = mask + (size_t)bglob * Lc;
    const float* xrow = x + (size_t)bglob * Lc * Tc;
    float sp = 0.f, msp = 0.f;
    for (int t = lane; t < Lc; t += 64) {
      int l0 = lbp[t];
      int m0 = mkp[t];
      msp += (float)m0;
      if (t < Lc - 1) {
        int l1 = lbp[t + 1];
        float m1 = (float)mkp[t + 1];
        sp += trans[l0 * Tc + l1] * m1 + xrow[(size_t)t * Tc + l0] * (float)m0;
      }
    }
#pragma unroll
    for (int off = 32; off; off >>= 1) {
      sp += __shfl_xor(sp, off);
      msp += __shfl_xor(msp, off);
    }
    if (lane == 0) {
      int last_idx = (int)msp - 1;
      int lt = lbp[last_idx];
      score_s[bb] = sp + startT[lbp[0]] + endT[lt]
                  + xrow[(size_t)(Lc - 1) * Tc + lt] * (float)mkp[Lc - 1];
      msum_s[bb] = msp;
    }
  }

  // ---- B-frags: 2 interleaved col-slices (jA, jA+1), 4 K-chunks each; 32 VGPRs ----
  bf16x8 BA0, BA1, BA2, BA3, BB0, BB1, BB2, BB3;
  {
    const float* tp_ = trans + jA;
#define LOADB(Q, DA, DB)                                                     \
    _Pragma("unroll") for (int e = 0; e < 8; ++e) {                          \
      DA[e] = f2bf(__expf(tp_[(32 * Q + 8 * khi + e) * Tc]));                \
      DB[e] = f2bf(__expf(tp_[(32 * Q + 8 * khi + e) * Tc + 1]));            \
    }
    LOADB(0, BA0, BB0) LOADB(1, BA1, BB1) LOADB(2, BA2, BB2) LOADB(3, BA3, BB3)
#undef LOADB
  }

  // ---- per-lane constant offsets ----
  const int aoff = crow * PSTR + 8 * khi;   // A-frag elem base
  const int woff = (4 * khi) * PSTR + jA;   // write elem base (even -> u32 aligned)
  const float* xp0 = x + (size_t)(bg0 + 4 * khi + 0) * Lc * Tc + jA;
  const float* xp1 = x + (size_t)(bg0 + 4 * khi + 1) * Lc * Tc + jA;
  const float* xp2 = x + (size_t)(bg0 + 4 * khi + 2) * Lc * Tc + jA;
  const float* xp3 = x + (size_t)(bg0 + 4 * khi + 3) * Lc * Tc + jA;
  const bool rlane = (w == 0) && (crow == 0);  // 4 lanes own rescale/c for 16 batches

  __syncthreads();  // mT staged

  // ---- init: alpha_0 = start + x_0; exact renorm by alpha_0[b][0] ----
  f32x2 st2 = *(const f32x2*)&startT[jA];
  f32x2 a0 = st2 + *(const f32x2*)xp0;
  f32x2 a1 = st2 + *(const f32x2*)xp1;
  f32x2 a2 = st2 + *(const f32x2*)xp2;
  f32x2 a3 = st2 + *(const f32x2*)xp3;
  if (rlane) {
    f32x4 cv = {a0.x, a1.x, a2.x, a3.x};
    *(f32x4*)&r_s[1][khi << 2] = cv;
  }
  __syncthreads();
  f32x4 cb = *(const f32x4*)&r_s[1][khi << 2];
  f32x2 Ao0 = {__expf(a0.x - cb.x), __expf(a0.y - cb.x)};
  f32x2 Ao1 = {__expf(a1.x - cb.y), __expf(a1.y - cb.y)};
  f32x2 Ao2 = {__expf(a2.x - cb.z), __expf(a2.y - cb.z)};
  f32x2 Ao3 = {__expf(a3.x - cb.w), __expf(a3.y - cb.w)};
  *(unsigned*)&Pl[PBUF + woff + 0 * PSTR] = (unsigned)f2bf_u(Ao0.x) | ((unsigned)f2bf_u(Ao0.y) << 16);
  *(unsigned*)&Pl[PBUF + woff + 1 * PSTR] = (unsigned)f2bf_u(Ao1.x) | ((unsigned)f2bf_u(Ao1.y) << 16);
  *(unsigned*)&Pl[PBUF + woff + 2 * PSTR] = (unsigned)f2bf_u(Ao2.x) | ((unsigned)f2bf_u(Ao2.y) << 16);
  *(unsigned*)&Pl[PBUF + woff + 3 * PSTR] = (unsigned)f2bf_u(Ao3.x) | ((unsigned)f2bf_u(Ao3.y) << 16);
  f32x4 c  = rlane ? cb : (f32x4){0.f, 0.f, 0.f, 0.f};
  f32x4 lr = {0.f, 0.f, 0.f, 0.f};   // log of scale applied by the CURRENT r (=1 initially)
  __syncthreads();                   // cb reads done -> safe to overwrite r_s[1]
  if (rlane) {
    f32x4 one = {1.f, 1.f, 1.f, 1.f};
    *(f32x4*)&r_s[1][khi << 2] = one;
  }
  // x prefetch, depth 2 (float2 per row)
  f32x2 xA0 = *(const f32x2*)(xp0 + Tc), xA1 = *(const f32x2*)(xp1 + Tc);
  f32x2 xA2 = *(const f32x2*)(xp2 + Tc), xA3 = *(const f32x2*)(xp3 + Tc);
  f32x2 xB0 = *(const f32x2*)(xp0 + 2 * Tc), xB1 = *(const f32x2*)(xp1 + 2 * Tc);
  f32x2 xB2 = *(const f32x2*)(xp2 + 2 * Tc), xB3 = *(const f32x2*)(xp3 + 2 * Tc);
  __syncthreads();                   // P[1], r_s[1] visible

  // Step t: S_t = Abar @ E; Abar_t = S_t * r_stale * exp(x_t) (masked);
  // c += mask ? lr : 0 at use time; r = 2^-E(S[0]) (exact), lr = E*ln2.
#define STEP(T, RB, WB, XA0, XA1, XA2, XA3) do {                               \
    bf16x8 Af0 = *(const bf16x8*)&Pl[(RB) * PBUF + aoff +  0];                 \
    bf16x8 Af1 = *(const bf16x8*)&Pl[(RB) * PBUF + aoff + 32];                 \
    bf16x8 Af2 = *(const bf16x8*)&Pl[(RB) * PBUF + aoff + 64];                 \
    bf16x8 Af3 = *(const bf16x8*)&Pl[(RB) * PBUF + aoff + 96];                 \
    f32x4 rr = *(const f32x4*)&r_s[RB][khi << 2];                              \
    unsigned mw = *(const unsigned*)&mT[T][khi << 2];                          \
    int tp = (T) + 2 < Lc ? (T) + 2 : Lc - 1;                                  \
    f32x2 xn0 = *(const f32x2*)(xp0 + (size_t)tp * Tc);                        \
    f32x2 xn1 = *(const f32x2*)(xp1 + (size_t)tp * Tc);                        \
    f32x2 xn2 = *(const f32x2*)(xp2 + (size_t)tp * Tc);                        \
    f32x2 xn3 = *(const f32x2*)(xp3 + (size_t)tp * Tc);                        \
    f32x2 ex0 = {__expf(XA0.x), __expf(XA0.y)};                                \
    f32x2 ex1 = {__expf(XA1.x), __expf(XA1.y)};                                \
    f32x2 ex2 = {__expf(XA2.x), __expf(XA2.y)};                                \
    f32x2 ex3 = {__expf(XA3.x), __expf(XA3.y)};                                \
    f32x4 CA = {0.f, 0.f, 0.f, 0.f};                                           \
    f32x4 CB = {0.f, 0.f, 0.f, 0.f};                                           \
    CA = __builtin_amdgcn_mfma_f32_16x16x32_bf16(Af0, BA0, CA, 0, 0, 0);       \
    CA = __builtin_amdgcn_mfma_f32_16x16x32_bf16(Af1, BA1, CA, 0, 0, 0);       \
    CA = __builtin_amdgcn_mfma_f32_16x16x32_bf16(Af2, BA2, CA, 0, 0, 0);       \
    CA = __builtin_amdgcn_mfma_f32_16x16x32_bf16(Af3, BA3, CA, 0, 0, 0);       \
    CB = __builtin_amdgcn_mfma_f32_16x16x32_bf16(Af0, BB0, CB, 0, 0, 0);       \
    CB = __builtin_amdgcn_mfma_f32_16x16x32_bf16(Af1, BB1, CB, 0, 0, 0);       \
    CB = __builtin_amdgcn_mfma_f32_16x16x32_bf16(Af2, BB2, CB, 0, 0, 0);       \
    CB = __builtin_amdgcn_mfma_f32_16x16x32_bf16(Af3, BB3, CB, 0, 0, 0);       \
    f32x2 v0 = {CA.x * rr.x * ex0.x, CB.x * rr.x * ex0.y};                     \
    f32x2 v1 = {CA.y * rr.y * ex1.x, CB.y * rr.y * ex1.y};                     \
    f32x2 v2 = {CA.z * rr.z * ex2.x, CB.z * rr.z * ex2.y};                     \
    f32x2 v3 = {CA.w * rr.w * ex3.x, CB.w * rr.w * ex3.y};                     \
    if (mw & 0x1u)       Ao0 = v0;                                             \
    if (mw & 0x100u)     Ao1 = v1;                                             \
    if (mw & 0x10000u)   Ao2 = v2;                                             \
    if (mw & 0x1000000u) Ao3 = v3;                                             \
    *(unsigned*)&Pl[(WB) * PBUF + woff + 0 * PSTR] =                           \
        (unsigned)f2bf_u(Ao0.x) | ((unsigned)f2bf_u(Ao0.y) << 16);             \
    *(unsigned*)&Pl[(WB) * PBUF + woff + 1 * PSTR] =                           \
        (unsigned)f2bf_u(Ao1.x) | ((unsigned)f2bf_u(Ao1.y) << 16);             \
    *(unsigned*)&Pl[(WB) * PBUF + woff + 2 * PSTR] =                           \
        (unsigned)f2bf_u(Ao2.x) | ((unsigned)f2bf_u(Ao2.y) << 16);             \
    *(unsigned*)&Pl[(WB) * PBUF + woff + 3 * PSTR] =                           \
        (unsigned)f2bf_u(Ao3.x) | ((unsigned)f2bf_u(Ao3.y) << 16);             \
    XA0 = xn0; XA1 = xn1; XA2 = xn2; XA3 = xn3;                                \
    if (rlane) {                                                               \
      c.x += (mw & 0x1u)       ? lr.x : 0.f;                                   \
      c.y += (mw & 0x100u)     ? lr.y : 0.f;                                   \
      c.z += (mw & 0x10000u)   ? lr.z : 0.f;                                   \
      c.w += (mw & 0x1000000u) ? lr.w : 0.f;                                   \
      int e0 = (int)((__float_as_uint(CA.x) >> 23) & 0xffu) - 127;             \
      int e1 = (int)((__float_as_uint(CA.y) >> 23) & 0xffu) - 127;             \
      int e2 = (int)((__float_as_uint(CA.z) >> 23) & 0xffu) - 127;             \
      int e3 = (int)((__float_as_uint(CA.w) >> 23) & 0xffu) - 127;             \
      lr.x = (float)e0 * 0.6931471805599453f;                                  \
      lr.y = (float)e1 * 0.6931471805599453f;                                  \
      lr.z = (float)e2 * 0.6931471805599453f;                                  \
      lr.w = (float)e3 * 0.6931471805599453f;                                  \
      f32x4 rv;                                                                \
      rv.x = __uint_as_float((unsigned)(127 - e0) << 23);                      \
      rv.y = __uint_as_float((unsigned)(127 - e1) << 23);                      \
      rv.z = __uint_as_float((unsigned)(127 - e2) << 23);                      \
      rv.w = __uint_as_float((unsigned)(127 - e3) << 23);                      \
      *(f32x4*)&r_s[WB][khi << 2] = rv;                                        \
    }                                                                          \
    bar_lgkm();                                                                \
  } while (0)

  for (int t = 1; t < Lc; t += 2) {
    STEP(t, 1, 0, xA0, xA1, xA2, xA3);
    if (t + 1 < Lc) { STEP(t + 1, 0, 1, xB0, xB1, xB2, xB3); }
  }
#undef STEP

  // ---- logZ_b = c_b + log(sum_j Abar[b][j] * exp(end[j])) ----
  if (rlane) {
    *(f32x4*)&c_s[khi << 2] = c;
  }
  f32x2 ee = {__expf(endT[jA]), __expf(endT[jA + 1])};
  float s0 = Ao0.x * ee.x + Ao0.y * ee.y;
  float s1 = Ao1.x * ee.x + Ao1.y * ee.y;
  float s2 = Ao2.x * ee.x + Ao2.y * ee.y;
  float s3 = Ao3.x * ee.x + Ao3.y * ee.y;
#pragma unroll
  for (int off = 1; off < 16; off <<= 1) {
    s0 += __shfl_xor(s0, off);
    s1 += __shfl_xor(s1, off);
    s2 += __shfl_xor(s2, off);
    s3 += __shfl_xor(s3, off);
  }
  if (crow == 0) {
    red[4 * khi + 0][w] = s0;
    red[4 * khi + 1][w] = s1;
    red[4 * khi + 2][w] = s2;
    red[4 * khi + 3][w] = s3;
  }
  __syncthreads();
  if (tid < GB) {
    float tot = 0.f;
#pragma unroll
    for (int ww = 0; ww < NW; ++ww) tot += red[tid][ww];
    float logZ = c_s[tid] + __logf(tot);
    diff_out[bg0 + tid] = logZ - score_s[tid];
    msum_out[bg0 + tid] = msum_s[tid];
  }
}

__global__ __launch_bounds__(512)
void crf_final(const float* __restrict__ diff, const float* __restrict__ msum,
               float* __restrict__ out)
{
  __shared__ float sd[512];
  __shared__ float sm[512];
  int t = threadIdx.x;
  sd[t] = diff[t];
  sm[t] = msum[t];
  __syncthreads();
  for (int s = 256; s > 0; s >>= 1) {
    if (t < s) { sd[t] += sd[t + s]; sm[t] += sm[t + s]; }
    __syncthreads();
  }
  if (t == 0) out[0] = sd[0] / sm[0];
}

extern "C" void kernel_launch(void* const* d_in, const int* in_sizes, int n_in,
                              void* d_out, int out_size, void* d_ws, size_t ws_size,
                              hipStream_t stream) {
  const float* x      = (const float*)d_in[0];
  const float* trans  = (const float*)d_in[1];
  const float* startT = (const float*)d_in[2];
  const float* endT   = (const float*)d_in[3];
  const int*   labels = (const int*)d_in[4];
  const int*   mask   = (const int*)d_in[5];
  float* out = (float*)d_out;
  float* ws  = (float*)d_ws;
  float* diff = ws;        // [512]
  float* msum = ws + Bc;   // [512]

  crf_forward<<<dim3(Bc / GB), dim3(256), 0, stream>>>(
      x, trans, startT, endT, labels, mask, diff, msum);
  crf_final<<<dim3(1), dim3(512), 0, stream>>>(diff, msum, out);
}